// Round 7
// baseline (252.502 us; speedup 1.0000x reference)
//
#include <hip/hip_runtime.h>
#include <hip/hip_cooperative_groups.h>

namespace cg = cooperative_groups;

typedef __attribute__((ext_vector_type(8))) short s16x8;
typedef __attribute__((ext_vector_type(4))) float f32x4;

#define DEV static __device__ __forceinline__

DEV float b2f(unsigned short u){
  unsigned int i = ((unsigned int)u) << 16;
  float f; __builtin_memcpy(&f, &i, 4); return f;
}
DEV unsigned short f2b(float f){
  unsigned int i; __builtin_memcpy(&i, &f, 4);
  i = i + 0x7fffu + ((i >> 16) & 1u);
  return (unsigned short)(i >> 16);
}
DEV f32x4 mfma16(s16x8 a, s16x8 b, f32x4 c){
  return __builtin_amdgcn_mfma_f32_16x16x32_bf16(a, b, c, 0, 0, 0);
}
DEV s16x8 ld8f(const float* p){
  const float4* q4 = (const float4*)p;
  float4 a = q4[0], b = q4[1];
  s16x8 r;
  r[0]=(short)f2b(a.x); r[1]=(short)f2b(a.y); r[2]=(short)f2b(a.z); r[3]=(short)f2b(a.w);
  r[4]=(short)f2b(b.x); r[5]=(short)f2b(b.y); r[6]=(short)f2b(b.z); r[7]=(short)f2b(b.w);
  return r;
}

struct Params {
  const float *x, *noise, *Wq, *Wk, *Wv, *lg, *lb, *gsl, *bsl, *gmlp, *bmlp;
  const float *wih, *whh, *bih, *bhh, *w1, *b1, *w2, *b2, *mu, *lsg;
  unsigned short* qws;   // [32][16][64] bf16, slot-padded
  float* slots;          // [256][64]
  float* U;              // [32][8][64]
  float* S;              // [32][8]
  float* outp;           // [256][64] f32
};

// ---------------------------------------------------------------------------
// device fn: slot init + LN_sl + q0 (validated k_init2 body). blocks 0..15.
// ---------------------------------------------------------------------------
__device__ void do_init(const Params& p, unsigned char* smem, int tid, int blk)
{
  unsigned short* st = (unsigned short*)(smem + 4608);
  float (*redS)[4] = (float (*)[4])(smem + 11264);
  float (*redQ)[4] = (float (*)[4])(smem + 11520);
  const int w = tid >> 6, ln = tid & 63;
  const int m16 = ln & 15, q = ln >> 4;
  const int r0 = blk * 16;
  const int cw = w*16 + m16;

  float sl[4], s1[4], s2[4];
  #pragma unroll
  for (int rr = 0; rr < 4; ++rr){
    int row = r0 + q*4 + rr;
    int k = row & 7;
    float v = p.mu[k*64 + cw] + (log1pf(expf(p.lsg[k*64 + cw])) + 1e-5f) * p.noise[row*64 + cw];
    sl[rr] = v;
    p.slots[row*64 + cw] = v;
    s1[rr] = v; s2[rr] = v*v;
  }
  #pragma unroll
  for (int m = 1; m < 16; m <<= 1){
    #pragma unroll
    for (int rr = 0; rr < 4; ++rr){
      s1[rr] += __shfl_xor(s1[rr], m);
      s2[rr] += __shfl_xor(s2[rr], m);
    }
  }
  if (m16 == 0){
    #pragma unroll
    for (int rr = 0; rr < 4; ++rr){ redS[q*4+rr][w] = s1[rr]; redQ[q*4+rr][w] = s2[rr]; }
  }
  __syncthreads();
  {
    const float gs = p.gsl[cw], bs = p.bsl[cw];
    #pragma unroll
    for (int rr = 0; rr < 4; ++rr){
      f32x4 aS = *(const f32x4*)redS[q*4+rr];
      f32x4 aQ = *(const f32x4*)redQ[q*4+rr];
      float tS = aS[0]+aS[1]+aS[2]+aS[3];
      float tQ = aQ[0]+aQ[1]+aQ[2]+aQ[3];
      float mean = tS*(1.f/64.f);
      float var  = tQ*(1.f/64.f) - mean*mean;
      float rs = rsqrtf(var + 1e-5f);
      st[(q*4+rr)*72 + cw] = f2b((sl[rr] - mean)*rs*gs + bs);
    }
  }
  __syncthreads();
  {
    f32x4 acc = {0,0,0,0};
    #pragma unroll
    for (int ks = 0; ks < 2; ++ks){
      s16x8 a = *(const s16x8*)(st + m16*72 + ks*32 + q*8);
      acc = mfma16(a, ld8f(p.Wq + cw*64 + ks*32 + q*8), acc);
    }
    #pragma unroll
    for (int rr = 0; rr < 4; ++rr){
      int row = r0 + q*4 + rr;
      int bb = row >> 3, kk = row & 7;
      p.qws[(bb*16 + kk)*64 + cw] = f2b(acc[rr] * 0.125f);
    }
  }
  {
    f32x4 z = {0,0,0,0};
    *(f32x4*)(p.U + r0*64 + tid*4) = z;
    if (tid < 16) p.S[r0 + tid] = 0.f;
    int b0 = blk * 2;
    ((unsigned int*)(p.qws + (b0*16 + 8)*64))[tid] = 0u;
    ((unsigned int*)(p.qws + ((b0+1)*16 + 8)*64))[tid] = 0u;
  }
  __threadfence();
}

// ---------------------------------------------------------------------------
// device fn: GRU + LN_mlp + MLP + residual + LN_sl + next-q (validated k_gru
// body). blocks 0..15. Also zeroes U,S and q-pads for the next iteration.
// ---------------------------------------------------------------------------
__device__ void do_gru(const Params& p, unsigned char* smem, int tid, int blk)
{
  unsigned short* ut  = (unsigned short*)(smem);
  unsigned short* ht  = (unsigned short*)(smem + 2304);
  unsigned short* st  = (unsigned short*)(smem + 4608);
  unsigned short* hid = (unsigned short*)(smem + 6912);
  float (*redS)[4] = (float (*)[4])(smem + 11264);
  float (*redQ)[4] = (float (*)[4])(smem + 11520);
  const int w = tid >> 6, ln = tid & 63;
  const int m16 = ln & 15, q = ln >> 4;
  const int r0 = blk * 16;
  const int cw = w*16 + m16;

  #pragma unroll
  for (int pr = 0; pr < 4; ++pr){
    int row = pr*4 + w;
    float sv = p.S[r0 + row];
    float uu = p.U[(r0 + row)*64 + ln] / sv;
    ut[row*72 + ln] = f2b(uu);
    ht[row*72 + ln] = f2b(p.slots[(r0 + row)*64 + ln]);
  }
  __syncthreads();

  f32x4 axr = {0,0,0,0}, axz = {0,0,0,0}, axn = {0,0,0,0};
  f32x4 ahr = {0,0,0,0}, ahz = {0,0,0,0}, ahn = {0,0,0,0};
  #pragma unroll
  for (int ks = 0; ks < 2; ++ks){
    s16x8 au = *(const s16x8*)(ut + m16*72 + ks*32 + q*8);
    s16x8 ah = *(const s16x8*)(ht + m16*72 + ks*32 + q*8);
    axr = mfma16(au, ld8f(p.wih + (      cw)*64 + ks*32 + q*8), axr);
    axz = mfma16(au, ld8f(p.wih + ( 64 + cw)*64 + ks*32 + q*8), axz);
    axn = mfma16(au, ld8f(p.wih + (128 + cw)*64 + ks*32 + q*8), axn);
    ahr = mfma16(ah, ld8f(p.whh + (      cw)*64 + ks*32 + q*8), ahr);
    ahz = mfma16(ah, ld8f(p.whh + ( 64 + cw)*64 + ks*32 + q*8), ahz);
    ahn = mfma16(ah, ld8f(p.whh + (128 + cw)*64 + ks*32 + q*8), ahn);
  }
  const float bxr = p.bih[cw], bxz = p.bih[64+cw], bxn = p.bih[128+cw];
  const float bhr = p.bhh[cw], bhz = p.bhh[64+cw], bhn = p.bhh[128+cw];
  float sp[4];
  #pragma unroll
  for (int rr = 0; rr < 4; ++rr){
    float xr = axr[rr] + bxr, xz = axz[rr] + bxz, xnv = axn[rr] + bxn;
    float hr = ahr[rr] + bhr, hz = ahz[rr] + bhz, hn = ahn[rr] + bhn;
    float rg = 1.f / (1.f + expf(-(xr + hr)));
    float zg = 1.f / (1.f + expf(-(xz + hz)));
    float ng = tanhf(xnv + rg*hn);
    float hv = b2f(ht[(q*4 + rr)*72 + cw]);
    sp[rr] = (1.f - zg)*ng + zg*hv;
  }

  float s1[4], s2[4];
  #pragma unroll
  for (int rr = 0; rr < 4; ++rr){ s1[rr] = sp[rr]; s2[rr] = sp[rr]*sp[rr]; }
  #pragma unroll
  for (int m = 1; m < 16; m <<= 1){
    #pragma unroll
    for (int rr = 0; rr < 4; ++rr){
      s1[rr] += __shfl_xor(s1[rr], m);
      s2[rr] += __shfl_xor(s2[rr], m);
    }
  }
  if (m16 == 0){
    #pragma unroll
    for (int rr = 0; rr < 4; ++rr){ redS[q*4+rr][w] = s1[rr]; redQ[q*4+rr][w] = s2[rr]; }
  }
  __syncthreads();
  float sl_[4];
  {
    const float gm = p.gmlp[cw], bm = p.bmlp[cw];
    #pragma unroll
    for (int rr = 0; rr < 4; ++rr){
      f32x4 aS = *(const f32x4*)redS[q*4+rr];
      f32x4 aQ = *(const f32x4*)redQ[q*4+rr];
      float tS = aS[0]+aS[1]+aS[2]+aS[3];
      float tQ = aQ[0]+aQ[1]+aQ[2]+aQ[3];
      float mean = tS*(1.f/64.f);
      float var  = tQ*(1.f/64.f) - mean*mean;
      float rs = rsqrtf(var + 1e-5f);
      sl_[rr] = (sp[rr] - mean)*rs*gm + bm;
      st[(q*4+rr)*72 + cw] = f2b(sl_[rr]);
    }
  }
  __syncthreads();

  #pragma unroll
  for (int t2 = 0; t2 < 2; ++t2){
    int col = (w*2 + t2)*16 + m16;
    f32x4 acc = {0,0,0,0};
    #pragma unroll
    for (int ks = 0; ks < 2; ++ks){
      s16x8 a = *(const s16x8*)(st + m16*72 + ks*32 + q*8);
      acc = mfma16(a, ld8f(p.w1 + col*64 + ks*32 + q*8), acc);
    }
    float bb = p.b1[col];
    #pragma unroll
    for (int rr = 0; rr < 4; ++rr)
      hid[(q*4+rr)*136 + col] = f2b(fmaxf(acc[rr] + bb, 0.f));
  }
  __syncthreads();

  float snew[4];
  {
    f32x4 acc = {0,0,0,0};
    #pragma unroll
    for (int ks = 0; ks < 4; ++ks){
      s16x8 a = *(const s16x8*)(hid + m16*136 + ks*32 + q*8);
      acc = mfma16(a, ld8f(p.w2 + cw*128 + ks*32 + q*8), acc);
    }
    float bb = p.b2[cw];
    #pragma unroll
    for (int rr = 0; rr < 4; ++rr){
      snew[rr] = sl_[rr] + acc[rr] + bb;
      int row = r0 + q*4 + rr;
      p.slots[row*64 + cw] = snew[rr];
      p.outp[row*64 + cw] = snew[rr];
    }
  }

  #pragma unroll
  for (int rr = 0; rr < 4; ++rr){ s1[rr] = snew[rr]; s2[rr] = snew[rr]*snew[rr]; }
  #pragma unroll
  for (int m = 1; m < 16; m <<= 1){
    #pragma unroll
    for (int rr = 0; rr < 4; ++rr){
      s1[rr] += __shfl_xor(s1[rr], m);
      s2[rr] += __shfl_xor(s2[rr], m);
    }
  }
  __syncthreads();
  if (m16 == 0){
    #pragma unroll
    for (int rr = 0; rr < 4; ++rr){ redS[q*4+rr][w] = s1[rr]; redQ[q*4+rr][w] = s2[rr]; }
  }
  __syncthreads();
  {
    const float gs = p.gsl[cw], bs = p.bsl[cw];
    #pragma unroll
    for (int rr = 0; rr < 4; ++rr){
      f32x4 aS = *(const f32x4*)redS[q*4+rr];
      f32x4 aQ = *(const f32x4*)redQ[q*4+rr];
      float tS = aS[0]+aS[1]+aS[2]+aS[3];
      float tQ = aQ[0]+aQ[1]+aQ[2]+aQ[3];
      float mean = tS*(1.f/64.f);
      float var  = tQ*(1.f/64.f) - mean*mean;
      float rs = rsqrtf(var + 1e-5f);
      st[(q*4+rr)*72 + cw] = f2b((snew[rr] - mean)*rs*gs + bs);
    }
  }
  __syncthreads();
  {
    f32x4 acc = {0,0,0,0};
    #pragma unroll
    for (int ks = 0; ks < 2; ++ks){
      s16x8 a = *(const s16x8*)(st + m16*72 + ks*32 + q*8);
      acc = mfma16(a, ld8f(p.Wq + cw*64 + ks*32 + q*8), acc);
    }
    #pragma unroll
    for (int rr = 0; rr < 4; ++rr){
      int row = r0 + q*4 + rr;
      int bb = row >> 3, kk = row & 7;
      p.qws[(bb*16 + kk)*64 + cw] = f2b(acc[rr] * 0.125f);
    }
  }
  {
    f32x4 z = {0,0,0,0};
    *(f32x4*)(p.U + r0*64 + tid*4) = z;
    if (tid < 16) p.S[r0 + tid] = 0.f;
    int b0 = blk * 2;
    ((unsigned int*)(p.qws + (b0*16 + 8)*64))[tid] = 0u;
    ((unsigned int*)(p.qws + ((b0+1)*16 + 8)*64))[tid] = 0u;
  }
  __threadfence();
}

// ---------------------------------------------------------------------------
// Fused persistent kernel. 512 blocks x 256 thr, 2 blocks/CU.
// Phase A: LN(x)+project k,v; k/v parked as MFMA A/B fragments in registers.
// 3 iters: scores -> in-reg softmax -> PV, all from registers; U/S via atomics;
// grid.sync; gru on blocks 0..15; grid.sync.
// ---------------------------------------------------------------------------
__global__ __launch_bounds__(256, 2) void k_fused(Params p)
{
  cg::grid_group grid = cg::this_grid();
  __shared__ __align__(16) unsigned char smem[22528];
  unsigned short* uni = (unsigned short*)smem;      // 4 waves x 2560 shorts
  float* U_blk = (float*)(smem + 20480);            // [8][64]

  const int tid = threadIdx.x;
  const int w = tid >> 6, ln = tid & 63;
  const int m16 = ln & 15, q = ln >> 4;
  const int blk = blockIdx.x;
  const int b = blk >> 4;
  const int nbase = (blk & 15) << 8;
  unsigned short* myuni = uni + w*2560;

  // ---- phase A: LN coeffs as bf16 frags ----
  s16x8 gfr[4], bfr[4];
  #pragma unroll
  for (int kb = 0; kb < 4; ++kb){
    gfr[kb] = ld8f(p.lg + kb*32 + q*8);
    bfr[kb] = ld8f(p.lb + kb*32 + q*8);
  }

  // LN(x) -> A-fragments in registers (lane owns its exact frag elements)
  s16x8 xA[4][4];   // [t][kb]
  #pragma unroll 2
  for (int t = 0; t < 4; ++t){
    long row = (long)b*4096 + nbase + w*64 + t*16 + m16;
    const float* xr = p.x + row*128;
    float4 xv[8];
    #pragma unroll
    for (int kb = 0; kb < 4; ++kb){
      xv[kb*2]   = *(const float4*)(xr + kb*32 + q*8);
      xv[kb*2+1] = *(const float4*)(xr + kb*32 + q*8 + 4);
    }
    float s1 = 0.f, s2 = 0.f;
    #pragma unroll
    for (int i = 0; i < 8; ++i){
      float4 v = xv[i];
      s1 += v.x + v.y + v.z + v.w;
      s2 += v.x*v.x + v.y*v.y + v.z*v.z + v.w*v.w;
    }
    s1 += __shfl_xor(s1, 16); s2 += __shfl_xor(s2, 16);
    s1 += __shfl_xor(s1, 32); s2 += __shfl_xor(s2, 32);
    float mean = s1 * (1.f/128.f);
    float var  = s2 * (1.f/128.f) - mean*mean;
    float rs = rsqrtf(var + 1e-5f);
    #pragma unroll
    for (int kb = 0; kb < 4; ++kb){
      const float* e0 = (const float*)&xv[kb*2];
      s16x8 fr;
      #pragma unroll
      for (int j = 0; j < 8; ++j){
        float g = b2f((unsigned short)gfr[kb][j]);
        float bb = b2f((unsigned short)bfr[kb][j]);
        fr[j] = (short)f2b((e0[j] - mean)*rs*g + bb);
      }
      xA[t][kb] = fr;
    }
  }

  // k projection -> A-fragments in registers (via wave-local LDS transform)
  s16x8 kA[4][2];   // [t][ks], A[m=n][k=h]
  {
    s16x8 bwk[4][4];
    #pragma unroll
    for (int nt = 0; nt < 4; ++nt)
      #pragma unroll
      for (int kb = 0; kb < 4; ++kb)
        bwk[kb][nt] = ld8f(p.Wk + (nt*16 + m16)*128 + kb*32 + q*8);
    #pragma unroll
    for (int t = 0; t < 4; ++t){
      f32x4 acc[4] = {{0,0,0,0},{0,0,0,0},{0,0,0,0},{0,0,0,0}};
      #pragma unroll
      for (int kb = 0; kb < 4; ++kb)
        #pragma unroll
        for (int nt = 0; nt < 4; ++nt)
          acc[nt] = mfma16(xA[t][kb], bwk[kb][nt], acc[nt]);
      __syncthreads();
      #pragma unroll
      for (int nt = 0; nt < 4; ++nt)
        #pragma unroll
        for (int rr = 0; rr < 4; ++rr)
          myuni[(q*4+rr)*72 + nt*16 + m16] = f2b(acc[nt][rr]);  // [n][h]
      __syncthreads();
      #pragma unroll
      for (int ks = 0; ks < 2; ++ks)
        kA[t][ks] = *(const s16x8*)(myuni + m16*72 + ks*32 + q*8);
    }
  }

  // v projection -> B-fragments in registers (transpose via wave-local LDS)
  s16x8 vB[4][2];   // [nt][pair], B[k=n][n'=h]
  {
    s16x8 bwv[4][4];
    #pragma unroll
    for (int nt = 0; nt < 4; ++nt)
      #pragma unroll
      for (int kb = 0; kb < 4; ++kb)
        bwv[kb][nt] = ld8f(p.Wv + (nt*16 + m16)*128 + kb*32 + q*8);
    #pragma unroll
    for (int pr = 0; pr < 2; ++pr){
      f32x4 accp[2][4];
      #pragma unroll
      for (int tl = 0; tl < 2; ++tl){
        #pragma unroll
        for (int nt = 0; nt < 4; ++nt){ f32x4 z = {0,0,0,0}; accp[tl][nt] = z; }
        #pragma unroll
        for (int kb = 0; kb < 4; ++kb)
          #pragma unroll
          for (int nt = 0; nt < 4; ++nt)
            accp[tl][nt] = mfma16(xA[pr*2+tl][kb], bwv[kb][nt], accp[tl][nt]);
      }
      __syncthreads();
      #pragma unroll
      for (int tl = 0; tl < 2; ++tl)
        #pragma unroll
        for (int nt = 0; nt < 4; ++nt){
          uint2 pv;
          pv.x = (unsigned int)f2b(accp[tl][nt][0]) | ((unsigned int)f2b(accp[tl][nt][1]) << 16);
          pv.y = (unsigned int)f2b(accp[tl][nt][2]) | ((unsigned int)f2b(accp[tl][nt][3]) << 16);
          *(uint2*)(myuni + (nt*16+m16)*40 + tl*16 + q*4) = pv;   // [h][n], stride 40
        }
      __syncthreads();
      #pragma unroll
      for (int nt = 0; nt < 4; ++nt)
        vB[nt][pr] = *(const s16x8*)(myuni + (nt*16+m16)*40 + q*8);
    }
  }

  if (blk < 16) do_init(p, smem, tid, blk);
  grid.sync();

  // ---- iterations ----
  for (int it = 0; it < 3; ++it){
    s16x8 bq[2];
    #pragma unroll
    for (int ks = 0; ks < 2; ++ks)
      bq[ks] = *(const s16x8*)(p.qws + (b*16 + m16)*64 + ks*32 + q*8);

    U_blk[tid] = 0.f; U_blk[tid + 256] = 0.f;

    float sacc = 0.f;
    #pragma unroll
    for (int t = 0; t < 4; ++t){
      f32x4 sc = {0,0,0,0};
      sc = mfma16(kA[t][0], bq[0], sc);
      sc = mfma16(kA[t][1], bq[1], sc);
      unsigned short ab[4];
      #pragma unroll
      for (int rr = 0; rr < 4; ++rr){
        float v = (m16 < 8) ? sc[rr] : -3.0e38f;
        float mx = v;
        mx = fmaxf(mx, __shfl_xor(mx, 1));
        mx = fmaxf(mx, __shfl_xor(mx, 2));
        mx = fmaxf(mx, __shfl_xor(mx, 4));
        mx = fmaxf(mx, __shfl_xor(mx, 8));
        float e = (m16 < 8) ? expf(v - mx) : 0.f;
        float sm = e;
        sm += __shfl_xor(sm, 1);
        sm += __shfl_xor(sm, 2);
        sm += __shfl_xor(sm, 4);
        sm += __shfl_xor(sm, 8);
        float a = e/sm + 1e-8f;
        ab[rr] = f2b(a);
        sacc += b2f(ab[rr]);
      }
      if (m16 < 8){
        uint2 pv;
        pv.x = (unsigned int)ab[0] | ((unsigned int)ab[1] << 16);
        pv.y = (unsigned int)ab[2] | ((unsigned int)ab[3] << 16);
        *(uint2*)(myuni + m16*72 + t*16 + q*4) = pv;   // aT[slot][n], stride 72
      }
    }
    __syncthreads();

    // PV: per h-tile nt, K=64 (2 chunks) over this wave's own n
    #pragma unroll
    for (int nt = 0; nt < 4; ++nt){
      f32x4 au = {0,0,0,0};
      #pragma unroll
      for (int pr = 0; pr < 2; ++pr){
        s16x8 aA = *(const s16x8*)(myuni + m16*72 + pr*32 + q*8);
        au = mfma16(aA, vB[nt][pr], au);
      }
      if (q < 2){
        #pragma unroll
        for (int rr = 0; rr < 4; ++rr)
          atomicAdd(&U_blk[(q*4+rr)*64 + nt*16 + m16], au[rr]);
      }
    }
    // S: reduce over q-groups, one atomic per (wave,slot)
    sacc += __shfl_xor(sacc, 16);
    sacc += __shfl_xor(sacc, 32);
    if (q == 0 && m16 < 8) atomicAdd(&p.S[b*8 + m16], sacc);
    __syncthreads();

    atomicAdd(&p.U[b*512 + tid], U_blk[tid]);
    atomicAdd(&p.U[b*512 + tid + 256], U_blk[tid + 256]);

    grid.sync();
    if (blk < 16) do_gru(p, smem, tid, blk);
    grid.sync();
  }
}

// ===========================================================================
// FALLBACK PATH: validated round-6 kernels (used if cooperative launch is
// unavailable). Byte-identical to round 6.
// ===========================================================================
__global__ __launch_bounds__(256) void k_lnkv(
    const float* __restrict__ x, const float* __restrict__ Wk,
    const float* __restrict__ Wv, const float* __restrict__ lg,
    const float* __restrict__ lb, unsigned short* __restrict__ kg,
    unsigned short* __restrict__ vt)
{
  __shared__ unsigned int xs[128 * 68];
  const int tid = threadIdx.x;
  const int w = tid >> 6, ln = tid & 63;
  const int m16 = ln & 15, q = ln >> 4;
  const int b = blockIdx.x >> 5;
  const int nbase = (blockIdx.x & 31) << 7;
  const long rowg0 = (long)b * 4096 + nbase;
  {
    const int half = ln >> 5;
    const int L = ln & 31;
    const float4 gl4 = *(const float4*)(lg + L*4);
    const float4 bl4 = *(const float4*)(lb + L*4);
    for (int i = 0; i < 16; i += 4){
      float4 xv[4];
      #pragma unroll
      for (int j = 0; j < 4; ++j){
        int r = w*32 + (i+j)*2 + half;
        xv[j] = *(const float4*)(x + (rowg0 + r)*128 + L*4);
      }
      #pragma unroll
      for (int j = 0; j < 4; ++j){
        int r = w*32 + (i+j)*2 + half;
        float4 v = xv[j];
        float s1 = v.x + v.y + v.z + v.w;
        float s2 = v.x*v.x + v.y*v.y + v.z*v.z + v.w*v.w;
        #pragma unroll
        for (int m = 16; m >= 1; m >>= 1){
          s1 += __shfl_xor(s1, m);
          s2 += __shfl_xor(s2, m);
        }
        float mean = s1 * (1.f/128.f);
        float var  = s2 * (1.f/128.f) - mean*mean;
        float rs = rsqrtf(var + 1e-5f);
        uint2 pk;
        pk.x = (unsigned int)f2b((v.x-mean)*rs*gl4.x + bl4.x) |
               ((unsigned int)f2b((v.y-mean)*rs*gl4.y + bl4.y) << 16);
        pk.y = (unsigned int)f2b((v.z-mean)*rs*gl4.z + bl4.z) |
               ((unsigned int)f2b((v.w-mean)*rs*gl4.w + bl4.w) << 16);
        *(uint2*)&xs[r*68 + L*2] = pk;
      }
    }
  }
  __syncthreads();
  s16x8 bw[4][8];
  #pragma unroll
  for (int nt = 0; nt < 8; ++nt){
    const float* Wp = (nt < 4) ? (Wk + (nt*16 + m16)*128) : (Wv + ((nt-4)*16 + m16)*128);
    #pragma unroll
    for (int kb = 0; kb < 4; ++kb) bw[kb][nt] = ld8f(Wp + kb*32 + q*8);
  }
  const f32x4 zf = {0.f, 0.f, 0.f, 0.f};
  #pragma unroll
  for (int mi = 0; mi < 2; ++mi){
    int n0 = (w*2 + mi) * 16;
    f32x4 acc[8];
    #pragma unroll
    for (int nt = 0; nt < 8; ++nt) acc[nt] = zf;
    #pragma unroll
    for (int kb = 0; kb < 4; ++kb){
      s16x8 af = *(const s16x8*)((const unsigned short*)(xs + (n0 + m16)*68) + kb*32 + q*8);
      #pragma unroll
      for (int nt = 0; nt < 8; ++nt) acc[nt] = mfma16(af, bw[kb][nt], acc[nt]);
    }
    #pragma unroll
    for (int nt = 0; nt < 4; ++nt){
      int h = nt*16 + m16;
      #pragma unroll
      for (int rr = 0; rr < 4; ++rr){
        long n = rowg0 + n0 + q*4 + rr;
        kg[n*64 + h] = f2b(acc[nt][rr]);
      }
    }
    #pragma unroll
    for (int nt = 4; nt < 8; ++nt){
      int h = (nt-4)*16 + m16;
      uint2 pv;
      pv.x = (unsigned int)f2b(acc[nt][0]) | ((unsigned int)f2b(acc[nt][1]) << 16);
      pv.y = (unsigned int)f2b(acc[nt][2]) | ((unsigned int)f2b(acc[nt][3]) << 16);
      long off = ((long)b*64 + h)*4096 + nbase + n0 + q*4;
      *(uint2*)(vt + off) = pv;
    }
  }
}

__global__ __launch_bounds__(256) void k_init2(
    const float* __restrict__ noise, const float* __restrict__ mu,
    const float* __restrict__ lsg, const float* __restrict__ gsl,
    const float* __restrict__ bsl, const float* __restrict__ Wq,
    float* __restrict__ slots, unsigned short* __restrict__ qws,
    float* __restrict__ U, float* __restrict__ S)
{
  __shared__ unsigned short st[16*72];
  __shared__ __align__(16) float redS[16][4];
  __shared__ __align__(16) float redQ[16][4];
  const int tid = threadIdx.x;
  const int w = tid >> 6, ln = tid & 63;
  const int m16 = ln & 15, q = ln >> 4;
  const int r0 = blockIdx.x * 16;
  const int cw = w*16 + m16;
  float sl[4], s1[4], s2[4];
  #pragma unroll
  for (int rr = 0; rr < 4; ++rr){
    int row = r0 + q*4 + rr;
    int k = row & 7;
    float v = mu[k*64 + cw] + (log1pf(expf(lsg[k*64 + cw])) + 1e-5f) * noise[row*64 + cw];
    sl[rr] = v; slots[row*64 + cw] = v; s1[rr] = v; s2[rr] = v*v;
  }
  #pragma unroll
  for (int m = 1; m < 16; m <<= 1){
    #pragma unroll
    for (int rr = 0; rr < 4; ++rr){ s1[rr] += __shfl_xor(s1[rr], m); s2[rr] += __shfl_xor(s2[rr], m); }
  }
  if (m16 == 0){
    #pragma unroll
    for (int rr = 0; rr < 4; ++rr){ redS[q*4+rr][w] = s1[rr]; redQ[q*4+rr][w] = s2[rr]; }
  }
  __syncthreads();
  {
    const float gs = gsl[cw], bs = bsl[cw];
    #pragma unroll
    for (int rr = 0; rr < 4; ++rr){
      f32x4 aS = *(const f32x4*)redS[q*4+rr];
      f32x4 aQ = *(const f32x4*)redQ[q*4+rr];
      float tS = aS[0]+aS[1]+aS[2]+aS[3];
      float tQ = aQ[0]+aQ[1]+aQ[2]+aQ[3];
      float mean = tS*(1.f/64.f);
      float var  = tQ*(1.f/64.f) - mean*mean;
      float rs = rsqrtf(var + 1e-5f);
      st[(q*4+rr)*72 + cw] = f2b((sl[rr] - mean)*rs*gs + bs);
    }
  }
  __syncthreads();
  {
    f32x4 acc = {0,0,0,0};
    #pragma unroll
    for (int ks = 0; ks < 2; ++ks){
      s16x8 a = *(const s16x8*)(st + m16*72 + ks*32 + q*8);
      acc = mfma16(a, ld8f(Wq + cw*64 + ks*32 + q*8), acc);
    }
    #pragma unroll
    for (int rr = 0; rr < 4; ++rr){
      int row = r0 + q*4 + rr;
      int bb = row >> 3, kk = row & 7;
      qws[(bb*16 + kk)*64 + cw] = f2b(acc[rr] * 0.125f);
    }
  }
  {
    f32x4 z = {0,0,0,0};
    *(f32x4*)(U + r0*64 + tid*4) = z;
    if (tid < 16) S[r0 + tid] = 0.f;
    int b0 = blockIdx.x * 2;
    ((unsigned int*)(qws + (b0*16 + 8)*64))[tid] = 0u;
    ((unsigned int*)(qws + ((b0+1)*16 + 8)*64))[tid] = 0u;
  }
}

__global__ __launch_bounds__(256) void k_attn(
    const unsigned short* __restrict__ kg, const unsigned short* __restrict__ vt,
    const unsigned short* __restrict__ qws, float* __restrict__ U, float* __restrict__ S)
{
  __shared__ float sc[256*17];
  __shared__ unsigned short aT[16*264];
  const int tid = threadIdx.x;
  const int w = tid >> 6, ln = tid & 63;
  const int m16 = ln & 15, q = ln >> 4;
  const int b = blockIdx.x >> 4;
  const int nbase = (blockIdx.x & 15) << 8;
  for (int i = tid; i < 8*264; i += 256) aT[8*264 + i] = 0;
  s16x8 bq[2];
  #pragma unroll
  for (int ks = 0; ks < 2; ++ks)
    bq[ks] = *(const s16x8*)(qws + (b*16 + m16)*64 + ks*32 + q*8);
  #pragma unroll
  for (int mi = 0; mi < 4; ++mi){
    int n0 = (w*4 + mi)*16;
    f32x4 acc = {0.f, 0.f, 0.f, 0.f};
    #pragma unroll
    for (int ks = 0; ks < 2; ++ks){
      s16x8 af = *(const s16x8*)(kg + ((long)b*4096 + nbase + n0 + m16)*64 + ks*32 + q*8);
      acc = mfma16(af, bq[ks], acc);
    }
    #pragma unroll
    for (int rr = 0; rr < 4; ++rr) sc[(n0 + q*4 + rr)*17 + m16] = acc[rr];
  }
  __syncthreads();
  {
    int r = tid;
    float a8[8], mx = -1e30f;
    #pragma unroll
    for (int j = 0; j < 8; ++j){ a8[j] = sc[r*17 + j]; mx = fmaxf(mx, a8[j]); }
    float ssum = 0.f;
    #pragma unroll
    for (int j = 0; j < 8; ++j){ a8[j] = expf(a8[j] - mx); ssum += a8[j]; }
    float inv = 1.f/ssum;
    #pragma unroll
    for (int j = 0; j < 8; ++j) aT[j*264 + r] = f2b(a8[j]*inv + 1e-8f);
  }
  __syncthreads();
  {
    int j = tid >> 5, c = tid & 31;
    float pp = 0.f;
    #pragma unroll
    for (int i = 0; i < 8; ++i) pp += b2f(aT[j*264 + c + 32*i]);
    #pragma unroll
    for (int m = 16; m >= 1; m >>= 1) pp += __shfl_xor(pp, m);
    if ((ln & 31) == 0) atomicAdd(&S[b*8 + j], pp);
  }
  {
    f32x4 acc = {0.f, 0.f, 0.f, 0.f};
    #pragma unroll
    for (int ks = 0; ks < 8; ++ks){
      s16x8 af = *(const s16x8*)(aT + m16*264 + ks*32 + q*8);
      s16x8 bf = *(const s16x8*)(vt + ((long)b*64 + w*16 + m16)*4096 + nbase + ks*32 + q*8);
      acc = mfma16(af, bf, acc);
    }
    #pragma unroll
    for (int rr = 0; rr < 4; ++rr){
      int slot = q*4 + rr;
      if (slot < 8) atomicAdd(&U[b*512 + slot*64 + w*16 + m16], acc[rr]);
    }
  }
}

__global__ __launch_bounds__(256) void k_gru(
    const float* __restrict__ U, const float* __restrict__ S, float* __restrict__ slots,
    const float* __restrict__ wih, const float* __restrict__ whh,
    const float* __restrict__ bih, const float* __restrict__ bhh,
    const float* __restrict__ w1, const float* __restrict__ b1p,
    const float* __restrict__ w2, const float* __restrict__ b2p,
    const float* __restrict__ gmlp, const float* __restrict__ bmlp,
    const float* __restrict__ gsl, const float* __restrict__ bsl,
    const float* __restrict__ Wq, unsigned short* __restrict__ qws,
    float* __restrict__ outp, float* __restrict__ Uz, float* __restrict__ Sz)
{
  __shared__ unsigned char sm[11776];
  Params p;
  p.U = (float*)U; p.S = (float*)S; p.slots = slots;
  p.wih = wih; p.whh = whh; p.bih = bih; p.bhh = bhh;
  p.w1 = w1; p.b1 = b1p; p.w2 = w2; p.b2 = b2p;
  p.gmlp = gmlp; p.bmlp = bmlp; p.gsl = gsl; p.bsl = bsl;
  p.Wq = Wq; p.qws = qws; p.outp = outp;
  (void)Uz; (void)Sz;
  do_gru(p, sm, threadIdx.x, blockIdx.x);
}

// ---------------------------------------------------------------------------
extern "C" void kernel_launch(void* const* d_in, const int* in_sizes, int n_in,
                              void* d_out, int out_size, void* d_ws, size_t ws_size,
                              hipStream_t stream)
{
  const float* x    = (const float*)d_in[0];
  const float* noise= (const float*)d_in[1];
  const float* Wq   = (const float*)d_in[2];
  const float* Wk   = (const float*)d_in[3];
  const float* Wv   = (const float*)d_in[4];
  const float* ling = (const float*)d_in[5];
  const float* linb = (const float*)d_in[6];
  const float* gsl  = (const float*)d_in[7];
  const float* bsl  = (const float*)d_in[8];
  const float* gmlp = (const float*)d_in[9];
  const float* bmlp = (const float*)d_in[10];
  const float* wih  = (const float*)d_in[11];
  const float* whh  = (const float*)d_in[12];
  const float* bih  = (const float*)d_in[13];
  const float* bhh  = (const float*)d_in[14];
  const float* w1   = (const float*)d_in[15];
  const float* b1p  = (const float*)d_in[16];
  const float* w2   = (const float*)d_in[17];
  const float* b2p  = (const float*)d_in[18];
  const float* mu   = (const float*)d_in[19];
  const float* lsg  = (const float*)d_in[20];

  char* ws = (char*)d_ws;
  unsigned short* kg   = (unsigned short*)(ws);
  unsigned short* vt   = (unsigned short*)(ws + 16777216);
  unsigned short* qws  = (unsigned short*)(ws + 33554432);
  float* slots         = (float*)(ws + 33619968);
  float* U             = (float*)(ws + 33685504);
  float* S             = (float*)(ws + 33751040);
  float* outp          = (float*)d_out;

  Params prm;
  prm.x = x; prm.noise = noise; prm.Wq = Wq; prm.Wk = Wk; prm.Wv = Wv;
  prm.lg = ling; prm.lb = linb; prm.gsl = gsl; prm.bsl = bsl;
  prm.gmlp = gmlp; prm.bmlp = bmlp; prm.wih = wih; prm.whh = whh;
  prm.bih = bih; prm.bhh = bhh; prm.w1 = w1; prm.b1 = b1p;
  prm.w2 = w2; prm.b2 = b2p; prm.mu = mu; prm.lsg = lsg;
  prm.qws = qws; prm.slots = slots; prm.U = U; prm.S = S; prm.outp = outp;

  bool coop = false;
  int nb = 0;
  if (hipOccupancyMaxActiveBlocksPerMultiprocessor(&nb, k_fused, 256, 0) == hipSuccess
      && nb >= 2){
    void* kp[1] = { (void*)&prm };
    if (hipLaunchCooperativeKernel(k_fused, dim3(512), dim3(256), kp, 0u, stream)
        == hipSuccess){
      coop = true;
    } else {
      (void)hipGetLastError();
    }
  }

  if (!coop){
    hipLaunchKernelGGL(k_lnkv, dim3(1024), dim3(256), 0, stream, x, Wk, Wv, ling, linb, kg, vt);
    hipLaunchKernelGGL(k_init2, dim3(16), dim3(256), 0, stream, noise, mu, lsg, gsl, bsl, Wq, slots, qws, U, S);
    for (int it = 0; it < 3; ++it){
      hipLaunchKernelGGL(k_attn, dim3(512), dim3(256), 0, stream, kg, vt, qws, U, S);
      hipLaunchKernelGGL(k_gru, dim3(16), dim3(256), 0, stream, U, S, slots,
                         wih, whh, bih, bhh, w1, b1p, w2, b2p, gmlp, bmlp, gsl, bsl, Wq,
                         qws, outp, U, S);
    }
  }
  (void)in_sizes; (void)n_in; (void)out_size; (void)ws_size;
}